// Round 13
// baseline (364.145 us; speedup 1.0000x reference)
//
#include <hip/hip_runtime.h>
#include <math.h>

#define LWI 96
#define LHI 96
#define HWD 384
#define NPIX 147456
#define LRPIX 9216
#define HID 256

typedef __attribute__((ext_vector_type(8))) _Float16 f16x8;
typedef __attribute__((ext_vector_type(4))) _Float16 f16x4;
typedef __attribute__((ext_vector_type(16))) float f32x16;

__device__ __forceinline__ float gelu_fast(float x){
  float x2 = x*x;
  float u = x*(-2.3021181f - 0.1029443f*x2);
  float e = exp2f(u);
  return x * __builtin_amdgcn_rcpf(1.0f + e);
}

// jax.image.resize 'bilinear' (half-pixel, clamp) at scale 4
__device__ __forceinline__ float lr_up_at(const float* __restrict__ lr, int c, int y, int x){
  float sy = (y+0.5f)*0.25f - 0.5f;
  float sx = (x+0.5f)*0.25f - 0.5f;
  float fy = floorf(sy), fx = floorf(sx);
  float ty = sy - fy, tx = sx - fx;
  int y0 = (int)fy, x0 = (int)fx;
  int y0c = min(max(y0,0),LHI-1), y1c = min(max(y0+1,0),LHI-1);
  int x0c = min(max(x0,0),LWI-1), x1c = min(max(x0+1,0),LWI-1);
  const float* p = lr + c*LRPIX;
  float v00 = p[y0c*LWI+x0c], v01 = p[y0c*LWI+x1c];
  float v10 = p[y1c*LWI+x0c], v11 = p[y1c*LWI+x1c];
  return (1.f-ty)*((1.f-tx)*v00 + tx*v01) + ty*((1.f-tx)*v10 + tx*v11);
}

// first conv (Cin=3): f32 planar in -> f16 channel-last out X[px][64]
__global__ __launch_bounds__(256) void conv3x3_f16out(
    const float* __restrict__ in, const float* __restrict__ w,
    const float* __restrict__ b, _Float16* __restrict__ out16){
  int tid = blockIdx.x*256 + threadIdx.x;
  int o = tid / LRPIX; int rem = tid - o*LRPIX;
  int y = rem / LWI;   int x = rem - y*LWI;
  int ou = __builtin_amdgcn_readfirstlane(o);
  float acc = b[ou];
  const float* wo = w + ou*27;
  for (int i=0;i<3;++i){
    const float* inp = in + i*LRPIX;
    #pragma unroll
    for (int dy=0;dy<3;++dy){
      int yy = y + dy - 1;
      bool yok = (yy>=0 && yy<LHI);
      #pragma unroll
      for (int dx=0;dx<3;++dx){
        int xx = x + dx - 1;
        float v = (yok && xx>=0 && xx<LWI) ? inp[yy*LWI+xx] : 0.0f;
        acc = fmaf(wo[i*9 + dy*3 + dx], v, acc);
      }
    }
  }
  out16[rem*64 + o] = (_Float16)gelu_fast(acc);
}

// ---- pack conv weights into A-frag order ----
__global__ __launch_bounds__(256) void pack_convw(
  const float* __restrict__ cw1, const float* __restrict__ cw2,
  const float* __restrict__ cw3, const float* __restrict__ xw0,
  const float* __restrict__ xw1,
  _Float16* __restrict__ WC, _Float16* __restrict__ WX)
{
  int i = blockIdx.x*256 + threadIdx.x;
  if (i < 110592){
    int cv = i / 36864; int s2 = i - cv*36864;
    int tkf = s2 >> 9; int s = s2 & 511;
    int tap = tkf >> 3; int ksfb = tkf & 7;
    int ks = ksfb >> 1; int fb = ksfb & 1;
    int slot = s >> 3; int e = s & 7;
    int oc = fb*32 + (slot & 31);
    int ic = ks*16 + (slot>>5)*8 + e;
    int dy = tap/3, dx = tap - (tap/3)*3;
    const float* src = (cv==0)?cw1:(cv==1)?cw2:cw3;
    WC[i] = (_Float16)src[((oc*64+ic)*3+dy)*3+dx];
  } else if (i < 118784){
    int j = i - 110592;
    int cv = j >> 12; int s2 = j & 4095;
    int ks = s2 >> 10; int fb = (s2 >> 9) & 1; int s = s2 & 511;
    int slot = s >> 3; int e = s & 7;
    int oc = fb*32 + (slot & 31);
    int ic = ks*16 + (slot>>5)*8 + e;
    WX[j] = (_Float16)((cv==0) ? xw0[oc*66+ic] : xw1[oc*64+ic]);
  }
}

// ---- MFMA conv3x3 Cin=Cout=64, f16 channel-last in/out, 8x8 px tile/block ----
__global__ __launch_bounds__(256) void conv_mfma_kernel(
    const _Float16* __restrict__ Xin, const _Float16* __restrict__ WC,
    const float* __restrict__ bias, _Float16* __restrict__ Xout, int cv)
{
  __shared__ _Float16 xs[100*64];        // 12.8KB, 16B-chunk XOR swizzle
  __shared__ float red[2][2][64][20];    // 20.5KB padded K-reduce buffer
  const int t = threadIdx.x;
  const int lane = t & 63;
  const int w = __builtin_amdgcn_readfirstlane(t >> 6);  // 0..3
  const int fb = w & 1, kh = w >> 1;
  const int g = lane >> 5;
  const int gx0 = blockIdx.x*8, gy0 = blockIdx.y*8;

  for (int i = t; i < 800; i += 256){
    int sp = i >> 3, c = i & 7;
    int ly = (sp*205)>>11; int lx = sp - ly*10;
    int gy = gy0 - 1 + ly, gx = gx0 - 1 + lx;
    f16x8 v = f16x8{};
    if (gy>=0 && gy<LHI && gx>=0 && gx<LWI)
      v = *(const f16x8*)(Xin + (gy*LWI+gx)*64 + c*8);
    *(f16x8*)(xs + sp*64 + ((c ^ (sp&7))*8)) = v;
  }
  __syncthreads();

  const _Float16* WCc = WC + cv*36864;
  const int p0 = lane & 31;
  const int py0 = p0 >> 3, px0 = p0 & 7;
  f32x16 acc0{}, acc1{};
  #pragma unroll
  for (int tap = 0; tap < 9; ++tap){
    const int dy = tap/3, dx = tap - (tap/3)*3;
    #pragma unroll
    for (int ksl = 0; ksl < 2; ++ksl){
      int ks = kh*2 + ksl;
      f16x8 A = *(const f16x8*)(WCc + ((tap*4+ks)*2+fb)*512 + lane*8);
      int sp0 = (py0+dy)*10 + (px0+dx);
      int sp1 = (py0+4+dy)*10 + (px0+dx);
      int c0 = ks*2 + g;
      f16x8 B0 = *(const f16x8*)(xs + sp0*64 + ((c0 ^ (sp0&7))*8));
      f16x8 B1 = *(const f16x8*)(xs + sp1*64 + ((c0 ^ (sp1&7))*8));
      acc0 = __builtin_amdgcn_mfma_f32_32x32x16_f16(A,B0,acc0,0,0,0);
      acc1 = __builtin_amdgcn_mfma_f32_32x32x16_f16(A,B1,acc1,0,0,0);
    }
  }
  if (kh == 1){
    #pragma unroll
    for (int r4=0;r4<4;++r4){
      float4 v0 = make_float4(acc0[r4*4],acc0[r4*4+1],acc0[r4*4+2],acc0[r4*4+3]);
      float4 v1 = make_float4(acc1[r4*4],acc1[r4*4+1],acc1[r4*4+2],acc1[r4*4+3]);
      *(float4*)&red[fb][0][lane][r4*4] = v0;
      *(float4*)&red[fb][1][lane][r4*4] = v1;
    }
  }
  __syncthreads();
  if (kh == 0){
    #pragma unroll
    for (int ph=0; ph<2; ++ph){
      const f32x16& acc = ph ? acc1 : acc0;
      int py = ph*4 + py0;
      int gpx = (gy0+py)*LWI + (gx0+px0);
      #pragma unroll
      for (int r4=0;r4<4;++r4){
        float4 rr = *(const float4*)&red[fb][ph][lane][r4*4];
        float4 bb = *(const float4*)&bias[fb*32 + 8*r4 + 4*g];
        f16x4 o;
        o[0] = (_Float16)gelu_fast(acc[r4*4+0] + rr.x + bb.x);
        o[1] = (_Float16)gelu_fast(acc[r4*4+1] + rr.y + bb.y);
        o[2] = (_Float16)gelu_fast(acc[r4*4+2] + rr.z + bb.z);
        o[3] = (_Float16)gelu_fast(acc[r4*4+3] + rr.w + bb.w);
        *(f16x4*)(Xout + gpx*64 + fb*32 + 8*r4 + 4*g) = o;
      }
    }
  }
}

// ---- MFMA conv1x1 64->64 ----
__global__ __launch_bounds__(256) void conv1x1_mfma(
    const _Float16* __restrict__ Xin, const _Float16* __restrict__ W1,
    const float* __restrict__ bias, _Float16* __restrict__ Xout, int dogelu)
{
  __shared__ _Float16 bufB[4096];
  const int t = threadIdx.x;
  const int lane = t & 63;
  const int w = __builtin_amdgcn_readfirstlane(t >> 6);
  const int fb = w & 1, ph = w >> 1;
  const int px0 = blockIdx.x * 64;
  #pragma unroll
  for (int h = 0; h < 2; ++h){
    int i = t + h*256;
    int p = i & 63, c = i >> 6;
    f16x8 v = *(const f16x8*)(Xin + (px0+p)*64 + c*8);
    *(f16x8*)(bufB + ((c>>1)*2 + (p>>5))*512 + ((p&31)+32*(c&1))*8) = v;
  }
  __syncthreads();
  f32x16 acc{};
  #pragma unroll
  for (int ks=0; ks<4; ++ks){
    f16x8 A = *(const f16x8*)(W1 + (ks*2+fb)*512 + lane*8);
    f16x8 B = *(const f16x8*)(bufB + (ks*2+ph)*512 + lane*8);
    acc = __builtin_amdgcn_mfma_f32_32x32x16_f16(A,B,acc,0,0,0);
  }
  const int p31 = lane & 31, hi = lane >> 5;
  int px = px0 + ph*32 + p31;
  #pragma unroll
  for (int q=0;q<4;++q){
    float4 bb = *(const float4*)&bias[fb*32 + q*8 + 4*hi];
    const float* bp = (const float*)&bb;
    f16x4 o;
    #pragma unroll
    for (int r=0;r<4;++r){
      float v = acc[q*4+r] + bp[r];
      o[r] = (_Float16)(dogelu ? gelu_fast(v) : v);
    }
    *(f16x4*)(Xout + px*64 + fb*32 + q*8 + 4*hi) = o;
  }
}

// ---- pack MLP weights ----
__global__ __launch_bounds__(256) void pack_weights(
  const float* __restrict__ mw0, const float* __restrict__ mw1,
  const float* __restrict__ mw2, const float* __restrict__ mw3,
  const float* __restrict__ mw4, const float* __restrict__ hkw,
  const float* __restrict__ hgw,
  const float* __restrict__ mb0, const float* __restrict__ mb1,
  const float* __restrict__ mb2, const float* __restrict__ mb3,
  const float* __restrict__ mb4, const float* __restrict__ hkb,
  const float* __restrict__ hgb,
  _Float16* __restrict__ WB, float* __restrict__ biasAll)
{
  int i = blockIdx.x*256 + threadIdx.x;
  if (i < 356352){
    int layer, local;
    if (i < 28672){ layer = 0; local = i; }
    else { layer = 1 + ((i-28672)>>16); local = (i-28672)&65535; }
    int ks = local >> 12; int r = local & 4095;
    int cb = r >> 9; int s2 = r & 511; int slot = s2 >> 3; int e = s2 & 7;
    int col = cb*32 + (slot & 31); int g = slot >> 5;
    int k = ks*16 + g*8 + e;
    float v = 0.f;
    if (layer == 0){ if (k < 106) v = mw0[k*256+col]; }
    else if (layer == 1) v = mw1[k*256+col];
    else if (layer == 2) v = mw2[k*256+col];
    else if (layer == 3) v = mw3[k*256+col];
    else if (layer == 4) v = mw4[k*256+col];
    else { if (col < 196) v = hkw[k*196+col]; else if (col < 200) v = hgw[k*4+col-196]; }
    WB[i] = (_Float16)v;
  } else if (i < 356352+1536){
    int j = i - 356352; int layer = j>>8; int col = j&255;
    float v = 0.f;
    if (layer==0) v=mb0[col]; else if (layer==1) v=mb1[col]; else if(layer==2) v=mb2[col];
    else if(layer==3) v=mb3[col]; else if(layer==4) v=mb4[col];
    else { if (col<196) v=hkb[col]; else if(col<200) v=hgb[col-196]; }
    biasAll[j] = v;
  }
}

// wave w computes feats [64w,64w+64) x 64 px; 4 MFMA per ks
template<int NKS>
__device__ __forceinline__ void mlp_pass4(const _Float16* __restrict__ Wl,
    const _Float16* __restrict__ buf, int lane, int w, f32x16 (&acc)[4]){
  acc[0]=f32x16{}; acc[1]=f32x16{}; acc[2]=f32x16{}; acc[3]=f32x16{};
  #pragma unroll
  for (int ks=0; ks<NKS; ++ks){
    const _Float16* wp = Wl + (ks*8 + 2*w)*512 + lane*8;
    f16x8 a0 = *(const f16x8*)(wp);
    f16x8 a1 = *(const f16x8*)(wp + 512);
    const _Float16* bp = buf + ks*1024 + lane*8;
    f16x8 b0 = *(const f16x8*)(bp);
    f16x8 b1 = *(const f16x8*)(bp + 512);
    acc[0] = __builtin_amdgcn_mfma_f32_32x32x16_f16(a0,b0,acc[0],0,0,0);
    acc[1] = __builtin_amdgcn_mfma_f32_32x32x16_f16(a0,b1,acc[1],0,0,0);
    acc[2] = __builtin_amdgcn_mfma_f32_32x32x16_f16(a1,b0,acc[2],0,0,0);
    acc[3] = __builtin_amdgcn_mfma_f32_32x32x16_f16(a1,b1,acc[3],0,0,0);
  }
}

// ---- MFMA MLP v7: 64 px/block, 4 waves x 64 feats, 32KB in-place ----
__global__ __launch_bounds__(256,4) void mlp_mfma7_kernel(
  const _Float16* __restrict__ feat16, const float* __restrict__ lr,
  const _Float16* __restrict__ WB, const float* __restrict__ biasAll,
  float* __restrict__ sr)
{
  __shared__ _Float16 buf[16384];   // 32KB
  const int t = threadIdx.x;
  const int lane = t & 63;
  const int w = __builtin_amdgcn_readfirstlane(t >> 6);   // 0..3
  const int p31 = lane & 31; const int hi = lane >> 5;

  {
    const int p = lane; const int q = w;
    const int px = blockIdx.x*64 + p;
    const int y = px / HWD; const int x = px - y*HWD;
    float lx = (x+0.5f)*0.25f - 0.5f;
    float ly = (y+0.5f)*0.25f - 0.5f;
    float cxf = fminf(fmaxf(rintf(lx),0.f),95.f);
    float cyf = fminf(fmaxf(rintf(ly),0.f),95.f);
    int base = (int)cyf*LWI + (int)cxf;
    auto zwrite = [&](int k, float v){
      buf[((k>>4)*2 + (p>>5))*512 + ((p&31) + 32*((k>>3)&1))*8 + (k&7)] = (_Float16)v;
    };
    auto zwriteh = [&](int k, _Float16 v){
      buf[((k>>4)*2 + (p>>5))*512 + ((p&31) + 32*((k>>3)&1))*8 + (k&7)] = v;
    };
    if (q < 2){
      const _Float16* fsrc = feat16 + base*64 + q*32;
      #pragma unroll
      for (int j=0;j<32;++j) zwriteh(q*32+j, fsrc[j]);
    } else if (q == 2){
      float xn = (x+0.5f)/384.0f*2.0f - 1.0f;
      float s = sinf(xn*3.14159265358979323846f);
      float c = cosf(xn*3.14159265358979323846f);
      #pragma unroll
      for (int b=0;b<10;++b){
        zwrite(64+4*b+0, s); zwrite(64+4*b+1, c);
        float s2 = 2.f*s*c; float c2 = 1.f - 2.f*s*s;
        s=s2; c=c2;
      }
      zwrite(104, lx-cxf); zwrite(105, ly-cyf);
    } else {
      float yn = (y+0.5f)/384.0f*2.0f - 1.0f;
      float s = sinf(yn*3.14159265358979323846f);
      float c = cosf(yn*3.14159265358979323846f);
      #pragma unroll
      for (int b=0;b<10;++b){
        zwrite(64+4*b+2, s); zwrite(64+4*b+3, c);
        float s2 = 2.f*s*c; float c2 = 1.f - 2.f*s*s;
        s=s2; c=c2;
      }
      #pragma unroll
      for (int k=106;k<112;++k) zwrite(k, 0.f);
    }
  }
  __syncthreads();

  #pragma unroll 1
  for (int L=0; L<5; ++L){
    static const int WOFFS[5] = {0,28672,94208,159744,225280};
    f32x16 acc[4];
    if (L==0) mlp_pass4<7>(WB, buf, lane, w, acc);
    else      mlp_pass4<16>(WB + WOFFS[L], buf, lane, w, acc);
    __syncthreads();
    const float* Bl = biasAll + L*256;
    #pragma unroll
    for (int i=0;i<2;++i){
      const int F = w*64 + i*32;
      #pragma unroll
      for (int q2=0;q2<4;++q2){
        float4 bs = *(const float4*)&Bl[F + q2*8 + 4*hi];
        const float* bp2 = (const float*)&bs;
        int ks2 = (F>>4) + (q2>>1); int g2 = q2&1;
        _Float16* dst = buf + (ks2*2)*512 + (p31 + 32*g2)*8 + 4*hi;
        #pragma unroll
        for (int pb=0;pb<2;++pb){
          const f32x16& a = acc[i*2+pb];
          f16x4 o;
          #pragma unroll
          for (int r=0;r<4;++r) o[r] = (_Float16)gelu_fast(a[q2*4+r] + bp2[r]);
          *(f16x4*)(dst + pb*512) = o;
        }
      }
    }
    __syncthreads();
  }

  {
    f32x16 acc[4];
    mlp_pass4<16>(WB + 290816, buf, lane, w, acc);
    __syncthreads();
    #pragma unroll
    for (int i=0;i<2;++i){
      const int F = w*64 + i*32;
      #pragma unroll
      for (int reg=0;reg<16;++reg){
        int f = F + (reg&3) + 8*(reg>>2) + 4*hi;
        if (f < 200){
          float bias = biasAll[1280 + f];
          buf[f*72 + p31]      = (_Float16)(acc[i*2+0][reg] + bias);
          buf[f*72 + 32 + p31] = (_Float16)(acc[i*2+1][reg] + bias);
        }
      }
    }
  }
  __syncthreads();

  {
    const int p = t & 63; const int hd = t >> 6;
    auto KL = [&](int col)->float { return (float)buf[col*72 + p]; };
    const float L2E = 1.4426950408889634f;
    float g0=KL(196),g1=KL(197),g2=KL(198),g3=KL(199);
    float gm = fmaxf(fmaxf(g0,g1),fmaxf(g2,g3));
    float e0=exp2f((g0-gm)*L2E),e1=exp2f((g1-gm)*L2E),
          e2=exp2f((g2-gm)*L2E),e3=exp2f((g3-gm)*L2E);
    float gate = ((hd==0)?e0:(hd==1)?e1:(hd==2)?e2:e3)/(e0+e1+e2+e3);
    float m = -1e30f;
    #pragma unroll
    for (int k=0;k<49;++k) m = fmaxf(m, KL(hd*49+k));
    float s = 0.f;
    float ev[49];
    #pragma unroll
    for (int k=0;k<49;++k){ float e=exp2f((KL(hd*49+k)-m)*L2E); s+=e; ev[k]=e; }
    float sc = gate/s;
    #pragma unroll
    for (int k=0;k<49;++k) buf[(hd*49+k)*72 + p] = (_Float16)(ev[k]*sc);
  }
  __syncthreads();

  {
    float kv[13];
    #pragma unroll
    for (int j=0;j<13;++j){
      int i = t + j*256;
      if (i < 3136){
        int k = i >> 6, p = i & 63;
        kv[j] = (float)buf[k*72+p] + (float)buf[(49+k)*72+p]
              + (float)buf[(98+k)*72+p] + (float)buf[(147+k)*72+p];
      }
    }
    __syncthreads();
    #pragma unroll
    for (int j=0;j<13;++j){
      int i = t + j*256;
      if (i < 3136){
        int k = i >> 6, p = i & 63;
        buf[k*72+p] = (_Float16)kv[j];
      }
    }
  }
  __syncthreads();

  if (t < 192){
    const int c = t >> 6; const int p = t & 63;
    const int px = blockIdx.x*64 + p;
    const int y = px / HWD; const int x = px - y*HWD;
    float lx = (x+0.5f)*0.25f - 0.5f;
    float ly = (y+0.5f)*0.25f - 0.5f;
    int cxi = (int)fminf(fmaxf(rintf(lx),0.f),95.f);
    int cyi = (int)fminf(fmaxf(rintf(ly),0.f),95.f);
    const float* lrc = lr + c*LRPIX;
    float acc = 0.f;
    bool interior = (cxi>=3 && cxi<=92 && cyi>=3 && cyi<=92);
    if (__all(interior)){
      const float* lrb = lrc + (cyi-3)*LWI + (cxi-3);
      #pragma unroll
      for (int k=0;k<49;++k){
        float km = (float)buf[k*72+p];
        acc = fmaf(km, lrb[(k/7)*LWI + (k - (k/7)*7)], acc);
      }
    } else {
      #pragma unroll
      for (int k=0;k<49;++k){
        float km = (float)buf[k*72+p];
        int oy = k/7 - 3, ox = k - (k/7)*7 - 3;
        int nyy = min(max(cyi+oy,0),95), nxx = min(max(cxi+ox,0),95);
        acc = fmaf(km, lrc[nyy*LWI+nxx], acc);
      }
    }
    sr[c*NPIX + px] = acc;
  }
}

// ---- refiner v3: 320 threads, f16 x6s/r1b (LDS ~39KB -> 4 blocks/CU),
// single-pass phases (conv1: 320 tasks, conv2: 288, conv3: 256) ----
__global__ __launch_bounds__(320) void refiner_group_kernel(
  const float* __restrict__ lr, const float* __restrict__ srg,
  const float* __restrict__ w0, const float* __restrict__ b0,
  const float* __restrict__ w1, const float* __restrict__ b1,
  const float* __restrict__ w2, const float* __restrict__ b2,
  float* __restrict__ resW)
{
  __shared__ _Float16 x6s[2][22][32];   // padded rows (64B-aligned), 2.8KB
  __shared__ float    r1a[16][20][20];  // 25.6KB (hot conv2 reads stay f32)
  __shared__ _Float16 r1b[16][18][20];  // 11.5KB
  const int g = blockIdx.z;
  const int tid = threadIdx.x;
  const int gx0 = blockIdx.x*16, gy0 = blockIdx.y*16;

  for (int i = tid; i < 2*22*22; i += 320){
    int ic = i / 484; int rem = i - ic*484; int yy = rem / 22; int xx = rem - yy*22;
    int ch = g*2 + ic;
    int gy = gy0 - 3 + yy, gx = gx0 - 3 + xx;
    float v = 0.f;
    if (gy>=0 && gy<HWD && gx>=0 && gx<HWD){
      int c = (ch<3)?ch:(ch-3);
      float lu = lr_up_at(lr, c, gy, gx);
      v = (ch < 3) ? lu : (srg[c*NPIX + gy*HWD + gx] - lu);
    }
    x6s[ic][yy][xx] = (_Float16)v;
  }
  __syncthreads();

  // conv1: one task per thread (16 oc x 20 rows = 320)
  {
    int o = tid / 20; int yy = tid - o*20;
    int og = g*16 + o;
    float bias = b0[og];
    float acc[20];
    #pragma unroll
    for (int j=0;j<20;++j) acc[j] = bias;
    #pragma unroll
    for (int ic=0; ic<2; ++ic){
      #pragma unroll
      for (int dyy=0; dyy<3; ++dyy){
        float row[22];
        #pragma unroll
        for (int j=0;j<22;++j) row[j] = (float)x6s[ic][yy+dyy][j];
        #pragma unroll
        for (int dxx=0; dxx<3; ++dxx){
          float wv = w0[((og*2+ic)*3+dyy)*3+dxx];
          #pragma unroll
          for (int j=0;j<20;++j) acc[j] = fmaf(wv, row[j+dxx], acc[j]);
        }
      }
    }
    int gyy = gy0 - 2 + yy;
    bool rok = (gyy>=0 && gyy<HWD);
    #pragma unroll
    for (int j=0;j<20;++j){
      int gxx = gx0 - 2 + j;
      r1a[o][yy][j] = (rok && gxx>=0 && gxx<HWD) ? gelu_fast(acc[j]) : 0.f;
    }
  }
  __syncthreads();

  // conv2: one task per thread (16 oc x 18 rows = 288); f32 r1a float4 reads
  if (tid < 288){
    int o = tid / 18; int yy = tid - o*18;
    int og = g*16 + o;
    float bias = b1[og];
    float acc[18];
    #pragma unroll
    for (int j=0;j<18;++j) acc[j] = bias;
    for (int ic=0; ic<16; ++ic){
      #pragma unroll
      for (int dyy=0; dyy<3; ++dyy){
        float row[20];
        #pragma unroll
        for (int q=0;q<5;++q)
          *(float4*)&row[q*4] = *(const float4*)&r1a[ic][yy+dyy][q*4];
        #pragma unroll
        for (int dxx=0; dxx<3; ++dxx){
          float wv = w1[((og*16+ic)*3+dyy)*3+dxx];
          #pragma unroll
          for (int j=0;j<18;++j) acc[j] = fmaf(wv, row[j+dxx], acc[j]);
        }
      }
    }
    int gyy = gy0 - 1 + yy;
    bool rok = (gyy>=0 && gyy<HWD);
    #pragma unroll
    for (int j=0;j<18;++j){
      int gxx = gx0 - 1 + j;
      r1b[o][yy][j] = (_Float16)((rok && gxx>=0 && gxx<HWD) ? gelu_fast(acc[j]) : 0.f);
    }
  }
  __syncthreads();

  // conv3: one px per thread (256)
  if (tid < 256){
    int ty = tid >> 4, tx = tid & 15;
    float a = b2[g];
    for (int ic=0; ic<16; ++ic){
      #pragma unroll
      for (int dyy=0; dyy<3; ++dyy){
        #pragma unroll
        for (int dxx=0; dxx<3; ++dxx){
          a = fmaf(w2[((g*16+ic)*3+dyy)*3+dxx], (float)r1b[ic][ty+dyy][tx+dxx], a);
        }
      }
    }
    resW[g*NPIX + (gy0+ty)*HWD + gx0+tx] = a;
  }
}

// gray-residual fusion: out = clip(lr_up + gray(sr+res) - gray(lr_up))
__global__ __launch_bounds__(256) void fuse_kernel(
  const float* __restrict__ lr, const float* __restrict__ srg,
  const float* __restrict__ resW, float* __restrict__ out)
{
  int p = blockIdx.x*256 + threadIdx.x;
  int y = p / HWD, x = p - y*HWD;
  float lu[3];
  float d = 0.f;
  const float cf0=0.2989f, cf1=0.587f, cf2=0.114f;
  lu[0] = lr_up_at(lr, 0, y, x);
  lu[1] = lr_up_at(lr, 1, y, x);
  lu[2] = lr_up_at(lr, 2, y, x);
  d += cf0*(srg[0*NPIX+p] + resW[0*NPIX+p] - lu[0]);
  d += cf1*(srg[1*NPIX+p] + resW[1*NPIX+p] - lu[1]);
  d += cf2*(srg[2*NPIX+p] + resW[2*NPIX+p] - lu[2]);
  #pragma unroll
  for (int c=0;c<3;++c){
    float o_ = lu[c] + d;
    out[c*NPIX + p] = fminf(fmaxf(o_, 0.f), 1.f);
  }
}

extern "C" void kernel_launch(void* const* d_in, const int* in_sizes, int n_in,
                              void* d_out, int out_size, void* d_ws, size_t ws_size,
                              hipStream_t stream){
  const float* lr  = (const float*)d_in[0];
  const float* ew0 = (const float*)d_in[1];  const float* eb0 = (const float*)d_in[2];
  const float* ew1 = (const float*)d_in[3];  const float* eb1 = (const float*)d_in[4];
  const float* ew2 = (const float*)d_in[5];  const float* eb2 = (const float*)d_in[6];
  const float* ew3 = (const float*)d_in[7];  const float* eb3 = (const float*)d_in[8];
  const float* cw0 = (const float*)d_in[9];  const float* cb0 = (const float*)d_in[10];
  const float* cw1 = (const float*)d_in[11]; const float* cb1 = (const float*)d_in[12];
  const float* mw0 = (const float*)d_in[13]; const float* mb0 = (const float*)d_in[14];
  const float* mw1 = (const float*)d_in[15]; const float* mb1 = (const float*)d_in[16];
  const float* mw2 = (const float*)d_in[17]; const float* mb2 = (const float*)d_in[18];
  const float* mw3 = (const float*)d_in[19]; const float* mb3 = (const float*)d_in[20];
  const float* mw4 = (const float*)d_in[21]; const float* mb4 = (const float*)d_in[22];
  const float* hkw = (const float*)d_in[23]; const float* hkb = (const float*)d_in[24];
  const float* hgw = (const float*)d_in[25]; const float* hgb = (const float*)d_in[26];
  const float* rw0 = (const float*)d_in[27]; const float* rb0 = (const float*)d_in[28];
  const float* rw1 = (const float*)d_in[29]; const float* rb1 = (const float*)d_in[30];
  const float* rw2 = (const float*)d_in[31]; const float* rb2 = (const float*)d_in[32];

  float* ws = (float*)d_ws;
  _Float16* X0 = (_Float16*)ws;                  // [9216][64] f16
  _Float16* X1 = (_Float16*)(ws + 294912);       // [9216][64] f16
  float* srp   = ws + 589824;                    // [3][384][384] f32
  _Float16* WB = (_Float16*)(ws + 1032192);      // 356352 f16
  _Float16* WC = (_Float16*)(ws + 1210368);      // 110592 f16
  float* biasAll = ws + 1265664;                 // 1536 f32
  float* resW  = ws + 1267200;                   // [3][NPIX] f32
  _Float16* WX = (_Float16*)(ws + 1709568);      // 8192 f16 (1x1 conv weights)

  pack_weights<<<1398,256,0,stream>>>(mw0,mw1,mw2,mw3,mw4,hkw,hgw,
      mb0,mb1,mb2,mb3,mb4,hkb,hgb, WB, biasAll);
  pack_convw<<<464,256,0,stream>>>(ew1, ew2, ew3, cw0, cw1, WC, WX);

  conv3x3_f16out<<<2304,256,0,stream>>>(lr, ew0, eb0, X0);
  conv_mfma_kernel<<<dim3(12,12),256,0,stream>>>(X0, WC, eb1, X1, 0);
  conv_mfma_kernel<<<dim3(12,12),256,0,stream>>>(X1, WC, eb2, X0, 1);
  conv_mfma_kernel<<<dim3(12,12),256,0,stream>>>(X0, WC, eb3, X1, 2);
  conv1x1_mfma<<<144,256,0,stream>>>(X1, WX,        cb0, X0, 1);
  conv1x1_mfma<<<144,256,0,stream>>>(X0, WX + 4096, cb1, X1, 0);

  mlp_mfma7_kernel<<<2304,256,0,stream>>>(X1, lr, WB, biasAll, srp);

  refiner_group_kernel<<<dim3(24,24,3),320,0,stream>>>(lr, srp,
      rw0,rb0, rw1,rb1, rw2,rb2, resW);
  fuse_kernel<<<576,256,0,stream>>>(lr, srp, resW, (float*)d_out);
}

// Round 14
// 320.147 us; speedup vs baseline: 1.1374x; 1.1374x over previous
//
#include <hip/hip_runtime.h>
#include <math.h>

#define LWI 96
#define LHI 96
#define HWD 384
#define NPIX 147456
#define LRPIX 9216
#define HID 256

typedef __attribute__((ext_vector_type(8))) _Float16 f16x8;
typedef __attribute__((ext_vector_type(4))) _Float16 f16x4;
typedef __attribute__((ext_vector_type(16))) float f32x16;

__device__ __forceinline__ float gelu_fast(float x){
  float x2 = x*x;
  float u = x*(-2.3021181f - 0.1029443f*x2);
  float e = exp2f(u);
  return x * __builtin_amdgcn_rcpf(1.0f + e);
}

// jax.image.resize 'bilinear' (half-pixel, clamp) at scale 4
__device__ __forceinline__ float lr_up_at(const float* __restrict__ lr, int c, int y, int x){
  float sy = (y+0.5f)*0.25f - 0.5f;
  float sx = (x+0.5f)*0.25f - 0.5f;
  float fy = floorf(sy), fx = floorf(sx);
  float ty = sy - fy, tx = sx - fx;
  int y0 = (int)fy, x0 = (int)fx;
  int y0c = min(max(y0,0),LHI-1), y1c = min(max(y0+1,0),LHI-1);
  int x0c = min(max(x0,0),LWI-1), x1c = min(max(x0+1,0),LWI-1);
  const float* p = lr + c*LRPIX;
  float v00 = p[y0c*LWI+x0c], v01 = p[y0c*LWI+x1c];
  float v10 = p[y1c*LWI+x0c], v11 = p[y1c*LWI+x1c];
  return (1.f-ty)*((1.f-tx)*v00 + tx*v01) + ty*((1.f-tx)*v10 + tx*v11);
}

// first conv (Cin=3): f32 planar in -> f16 channel-last out X[px][64]
__global__ __launch_bounds__(256) void conv3x3_f16out(
    const float* __restrict__ in, const float* __restrict__ w,
    const float* __restrict__ b, _Float16* __restrict__ out16){
  int tid = blockIdx.x*256 + threadIdx.x;
  int o = tid / LRPIX; int rem = tid - o*LRPIX;
  int y = rem / LWI;   int x = rem - y*LWI;
  int ou = __builtin_amdgcn_readfirstlane(o);
  float acc = b[ou];
  const float* wo = w + ou*27;
  for (int i=0;i<3;++i){
    const float* inp = in + i*LRPIX;
    #pragma unroll
    for (int dy=0;dy<3;++dy){
      int yy = y + dy - 1;
      bool yok = (yy>=0 && yy<LHI);
      #pragma unroll
      for (int dx=0;dx<3;++dx){
        int xx = x + dx - 1;
        float v = (yok && xx>=0 && xx<LWI) ? inp[yy*LWI+xx] : 0.0f;
        acc = fmaf(wo[i*9 + dy*3 + dx], v, acc);
      }
    }
  }
  out16[rem*64 + o] = (_Float16)gelu_fast(acc);
}

// ---- pack ALL weights (MLP frag-major, conv A-frag, 1x1 A-frag) ----
__global__ __launch_bounds__(256) void pack_all(
  const float* __restrict__ mw0, const float* __restrict__ mw1,
  const float* __restrict__ mw2, const float* __restrict__ mw3,
  const float* __restrict__ mw4, const float* __restrict__ hkw,
  const float* __restrict__ hgw,
  const float* __restrict__ mb0, const float* __restrict__ mb1,
  const float* __restrict__ mb2, const float* __restrict__ mb3,
  const float* __restrict__ mb4, const float* __restrict__ hkb,
  const float* __restrict__ hgb,
  const float* __restrict__ cw1, const float* __restrict__ cw2,
  const float* __restrict__ cw3, const float* __restrict__ xw0,
  const float* __restrict__ xw1,
  _Float16* __restrict__ WB, float* __restrict__ biasAll,
  _Float16* __restrict__ WC, _Float16* __restrict__ WX)
{
  int i = blockIdx.x*256 + threadIdx.x;
  if (i < 356352){
    int layer, local;
    if (i < 28672){ layer = 0; local = i; }
    else { layer = 1 + ((i-28672)>>16); local = (i-28672)&65535; }
    int ks = local >> 12; int r = local & 4095;
    int cb = r >> 9; int s2 = r & 511; int slot = s2 >> 3; int e = s2 & 7;
    int col = cb*32 + (slot & 31); int g = slot >> 5;
    int k = ks*16 + g*8 + e;
    float v = 0.f;
    if (layer == 0){ if (k < 106) v = mw0[k*256+col]; }
    else if (layer == 1) v = mw1[k*256+col];
    else if (layer == 2) v = mw2[k*256+col];
    else if (layer == 3) v = mw3[k*256+col];
    else if (layer == 4) v = mw4[k*256+col];
    else { if (col < 196) v = hkw[k*196+col]; else if (col < 200) v = hgw[k*4+col-196]; }
    WB[i] = (_Float16)v;
  } else if (i < 357888){
    int j = i - 356352; int layer = j>>8; int col = j&255;
    float v = 0.f;
    if (layer==0) v=mb0[col]; else if (layer==1) v=mb1[col]; else if(layer==2) v=mb2[col];
    else if(layer==3) v=mb3[col]; else if(layer==4) v=mb4[col];
    else { if (col<196) v=hkb[col]; else if(col<200) v=hgb[col-196]; }
    biasAll[j] = v;
  } else if (i < 468480){
    int j = i - 357888;
    int cv = j / 36864; int s2 = j - cv*36864;
    int tkf = s2 >> 9; int s = s2 & 511;
    int tap = tkf >> 3; int ksfb = tkf & 7;
    int ks = ksfb >> 1; int fb = ksfb & 1;
    int slot = s >> 3; int e = s & 7;
    int oc = fb*32 + (slot & 31);
    int ic = ks*16 + (slot>>5)*8 + e;
    int dy = tap/3, dx = tap - (tap/3)*3;
    const float* src = (cv==0)?cw1:(cv==1)?cw2:cw3;
    WC[j] = (_Float16)src[((oc*64+ic)*3+dy)*3+dx];
  } else if (i < 476672){
    int j = i - 468480;
    int cv = j >> 12; int s2 = j & 4095;
    int ks = s2 >> 10; int fb = (s2 >> 9) & 1; int s = s2 & 511;
    int slot = s >> 3; int e = s & 7;
    int oc = fb*32 + (slot & 31);
    int ic = ks*16 + (slot>>5)*8 + e;
    WX[j] = (_Float16)((cv==0) ? xw0[oc*66+ic] : xw1[oc*64+ic]);
  }
}

// ---- MFMA conv3x3 Cin=Cout=64, f16 channel-last in/out, 8x8 px tile/block ----
__global__ __launch_bounds__(256) void conv_mfma_kernel(
    const _Float16* __restrict__ Xin, const _Float16* __restrict__ WC,
    const float* __restrict__ bias, _Float16* __restrict__ Xout, int cv)
{
  __shared__ _Float16 xs[100*64];        // 12.8KB, 16B-chunk XOR swizzle
  __shared__ float red[2][2][64][20];    // 20.5KB padded K-reduce buffer
  const int t = threadIdx.x;
  const int lane = t & 63;
  const int w = __builtin_amdgcn_readfirstlane(t >> 6);  // 0..3
  const int fb = w & 1, kh = w >> 1;
  const int g = lane >> 5;
  const int gx0 = blockIdx.x*8, gy0 = blockIdx.y*8;

  for (int i = t; i < 800; i += 256){
    int sp = i >> 3, c = i & 7;
    int ly = (sp*205)>>11; int lx = sp - ly*10;
    int gy = gy0 - 1 + ly, gx = gx0 - 1 + lx;
    f16x8 v = f16x8{};
    if (gy>=0 && gy<LHI && gx>=0 && gx<LWI)
      v = *(const f16x8*)(Xin + (gy*LWI+gx)*64 + c*8);
    *(f16x8*)(xs + sp*64 + ((c ^ (sp&7))*8)) = v;
  }
  __syncthreads();

  const _Float16* WCc = WC + cv*36864;
  const int p0 = lane & 31;
  const int py0 = p0 >> 3, px0 = p0 & 7;
  f32x16 acc0{}, acc1{};
  #pragma unroll
  for (int tap = 0; tap < 9; ++tap){
    const int dy = tap/3, dx = tap - (tap/3)*3;
    #pragma unroll
    for (int ksl = 0; ksl < 2; ++ksl){
      int ks = kh*2 + ksl;
      f16x8 A = *(const f16x8*)(WCc + ((tap*4+ks)*2+fb)*512 + lane*8);
      int sp0 = (py0+dy)*10 + (px0+dx);
      int sp1 = (py0+4+dy)*10 + (px0+dx);
      int c0 = ks*2 + g;
      f16x8 B0 = *(const f16x8*)(xs + sp0*64 + ((c0 ^ (sp0&7))*8));
      f16x8 B1 = *(const f16x8*)(xs + sp1*64 + ((c0 ^ (sp1&7))*8));
      acc0 = __builtin_amdgcn_mfma_f32_32x32x16_f16(A,B0,acc0,0,0,0);
      acc1 = __builtin_amdgcn_mfma_f32_32x32x16_f16(A,B1,acc1,0,0,0);
    }
  }
  if (kh == 1){
    #pragma unroll
    for (int r4=0;r4<4;++r4){
      float4 v0 = make_float4(acc0[r4*4],acc0[r4*4+1],acc0[r4*4+2],acc0[r4*4+3]);
      float4 v1 = make_float4(acc1[r4*4],acc1[r4*4+1],acc1[r4*4+2],acc1[r4*4+3]);
      *(float4*)&red[fb][0][lane][r4*4] = v0;
      *(float4*)&red[fb][1][lane][r4*4] = v1;
    }
  }
  __syncthreads();
  if (kh == 0){
    #pragma unroll
    for (int ph=0; ph<2; ++ph){
      const f32x16& acc = ph ? acc1 : acc0;
      int py = ph*4 + py0;
      int gpx = (gy0+py)*LWI + (gx0+px0);
      #pragma unroll
      for (int r4=0;r4<4;++r4){
        float4 rr = *(const float4*)&red[fb][ph][lane][r4*4];
        float4 bb = *(const float4*)&bias[fb*32 + 8*r4 + 4*g];
        f16x4 o;
        o[0] = (_Float16)gelu_fast(acc[r4*4+0] + rr.x + bb.x);
        o[1] = (_Float16)gelu_fast(acc[r4*4+1] + rr.y + bb.y);
        o[2] = (_Float16)gelu_fast(acc[r4*4+2] + rr.z + bb.z);
        o[3] = (_Float16)gelu_fast(acc[r4*4+3] + rr.w + bb.w);
        *(f16x4*)(Xout + gpx*64 + fb*32 + 8*r4 + 4*g) = o;
      }
    }
  }
}

// ---- fused MFMA conv1x1 pair (both 1x1s are pointwise -> one block, 2 GEMMs)
__global__ __launch_bounds__(256) void conv1x1_pair_mfma(
    const _Float16* __restrict__ Xin, const _Float16* __restrict__ WX,
    const float* __restrict__ b0, const float* __restrict__ b1,
    _Float16* __restrict__ Xout)
{
  __shared__ _Float16 bufB[4096];   // input acts, B-frag layout
  __shared__ _Float16 bufC[4096];   // intermediate acts, B-frag layout
  const int t = threadIdx.x;
  const int lane = t & 63;
  const int w = __builtin_amdgcn_readfirstlane(t >> 6);
  const int fb = w & 1, ph = w >> 1;
  const int px0 = blockIdx.x * 64;
  const int p31 = lane & 31, hi = lane >> 5;

  #pragma unroll
  for (int h = 0; h < 2; ++h){
    int i = t + h*256;
    int p = i & 63, c = i >> 6;
    f16x8 v = *(const f16x8*)(Xin + (px0+p)*64 + c*8);
    *(f16x8*)(bufB + ((c>>1)*2 + (p>>5))*512 + ((p&31)+32*(c&1))*8) = v;
  }
  __syncthreads();

  // GEMM 1 (cond_w0, gelu) -> bufC (B-frag layout)
  {
    f32x16 acc{};
    #pragma unroll
    for (int ks=0; ks<4; ++ks){
      f16x8 A = *(const f16x8*)(WX + (ks*2+fb)*512 + lane*8);
      f16x8 B = *(const f16x8*)(bufB + (ks*2+ph)*512 + lane*8);
      acc = __builtin_amdgcn_mfma_f32_32x32x16_f16(A,B,acc,0,0,0);
    }
    #pragma unroll
    for (int q=0;q<4;++q){
      float4 bb = *(const float4*)&b0[fb*32 + q*8 + 4*hi];
      const float* bp = (const float*)&bb;
      f16x4 o;
      #pragma unroll
      for (int r=0;r<4;++r) o[r] = (_Float16)gelu_fast(acc[q*4+r] + bp[r]);
      _Float16* dst = bufC + ((fb*2+(q>>1))*2 + ph)*512 + (p31 + 32*(q&1))*8 + 4*hi;
      *(f16x4*)dst = o;
    }
  }
  __syncthreads();

  // GEMM 2 (cond_w1, no gelu) -> Xout channel-last
  {
    f32x16 acc{};
    #pragma unroll
    for (int ks=0; ks<4; ++ks){
      f16x8 A = *(const f16x8*)(WX + 4096 + (ks*2+fb)*512 + lane*8);
      f16x8 B = *(const f16x8*)(bufC + (ks*2+ph)*512 + lane*8);
      acc = __builtin_amdgcn_mfma_f32_32x32x16_f16(A,B,acc,0,0,0);
    }
    int px = px0 + ph*32 + p31;
    #pragma unroll
    for (int q=0;q<4;++q){
      float4 bb = *(const float4*)&b1[fb*32 + q*8 + 4*hi];
      const float* bp = (const float*)&bb;
      f16x4 o;
      #pragma unroll
      for (int r=0;r<4;++r) o[r] = (_Float16)(acc[q*4+r] + bp[r]);
      *(f16x4*)(Xout + px*64 + fb*32 + q*8 + 4*hi) = o;
    }
  }
}

// wave w computes feats [64w,64w+64) x 64 px; 4 MFMA per ks
template<int NKS>
__device__ __forceinline__ void mlp_pass4(const _Float16* __restrict__ Wl,
    const _Float16* __restrict__ buf, int lane, int w, f32x16 (&acc)[4]){
  acc[0]=f32x16{}; acc[1]=f32x16{}; acc[2]=f32x16{}; acc[3]=f32x16{};
  #pragma unroll
  for (int ks=0; ks<NKS; ++ks){
    const _Float16* wp = Wl + (ks*8 + 2*w)*512 + lane*8;
    f16x8 a0 = *(const f16x8*)(wp);
    f16x8 a1 = *(const f16x8*)(wp + 512);
    const _Float16* bp = buf + ks*1024 + lane*8;
    f16x8 b0 = *(const f16x8*)(bp);
    f16x8 b1 = *(const f16x8*)(bp + 512);
    acc[0] = __builtin_amdgcn_mfma_f32_32x32x16_f16(a0,b0,acc[0],0,0,0);
    acc[1] = __builtin_amdgcn_mfma_f32_32x32x16_f16(a0,b1,acc[1],0,0,0);
    acc[2] = __builtin_amdgcn_mfma_f32_32x32x16_f16(a1,b0,acc[2],0,0,0);
    acc[3] = __builtin_amdgcn_mfma_f32_32x32x16_f16(a1,b1,acc[3],0,0,0);
  }
}

// ---- MFMA MLP v7: 64 px/block, 4 waves x 64 feats, 32KB in-place ----
__global__ __launch_bounds__(256,4) void mlp_mfma7_kernel(
  const _Float16* __restrict__ feat16, const float* __restrict__ lr,
  const _Float16* __restrict__ WB, const float* __restrict__ biasAll,
  float* __restrict__ sr)
{
  __shared__ _Float16 buf[16384];   // 32KB
  const int t = threadIdx.x;
  const int lane = t & 63;
  const int w = __builtin_amdgcn_readfirstlane(t >> 6);   // 0..3
  const int p31 = lane & 31; const int hi = lane >> 5;

  {
    const int p = lane; const int q = w;
    const int px = blockIdx.x*64 + p;
    const int y = px / HWD; const int x = px - y*HWD;
    float lx = (x+0.5f)*0.25f - 0.5f;
    float ly = (y+0.5f)*0.25f - 0.5f;
    float cxf = fminf(fmaxf(rintf(lx),0.f),95.f);
    float cyf = fminf(fmaxf(rintf(ly),0.f),95.f);
    int base = (int)cyf*LWI + (int)cxf;
    auto zwrite = [&](int k, float v){
      buf[((k>>4)*2 + (p>>5))*512 + ((p&31) + 32*((k>>3)&1))*8 + (k&7)] = (_Float16)v;
    };
    auto zwriteh = [&](int k, _Float16 v){
      buf[((k>>4)*2 + (p>>5))*512 + ((p&31) + 32*((k>>3)&1))*8 + (k&7)] = v;
    };
    if (q < 2){
      const _Float16* fsrc = feat16 + base*64 + q*32;
      #pragma unroll
      for (int j=0;j<32;++j) zwriteh(q*32+j, fsrc[j]);
    } else if (q == 2){
      float xn = (x+0.5f)/384.0f*2.0f - 1.0f;
      float s = sinf(xn*3.14159265358979323846f);
      float c = cosf(xn*3.14159265358979323846f);
      #pragma unroll
      for (int b=0;b<10;++b){
        zwrite(64+4*b+0, s); zwrite(64+4*b+1, c);
        float s2 = 2.f*s*c; float c2 = 1.f - 2.f*s*s;
        s=s2; c=c2;
      }
      zwrite(104, lx-cxf); zwrite(105, ly-cyf);
    } else {
      float yn = (y+0.5f)/384.0f*2.0f - 1.0f;
      float s = sinf(yn*3.14159265358979323846f);
      float c = cosf(yn*3.14159265358979323846f);
      #pragma unroll
      for (int b=0;b<10;++b){
        zwrite(64+4*b+2, s); zwrite(64+4*b+3, c);
        float s2 = 2.f*s*c; float c2 = 1.f - 2.f*s*s;
        s=s2; c=c2;
      }
      #pragma unroll
      for (int k=106;k<112;++k) zwrite(k, 0.f);
    }
  }
  __syncthreads();

  #pragma unroll 1
  for (int L=0; L<5; ++L){
    static const int WOFFS[5] = {0,28672,94208,159744,225280};
    f32x16 acc[4];
    if (L==0) mlp_pass4<7>(WB, buf, lane, w, acc);
    else      mlp_pass4<16>(WB + WOFFS[L], buf, lane, w, acc);
    __syncthreads();
    const float* Bl = biasAll + L*256;
    #pragma unroll
    for (int i=0;i<2;++i){
      const int F = w*64 + i*32;
      #pragma unroll
      for (int q2=0;q2<4;++q2){
        float4 bs = *(const float4*)&Bl[F + q2*8 + 4*hi];
        const float* bp2 = (const float*)&bs;
        int ks2 = (F>>4) + (q2>>1); int g2 = q2&1;
        _Float16* dst = buf + (ks2*2)*512 + (p31 + 32*g2)*8 + 4*hi;
        #pragma unroll
        for (int pb=0;pb<2;++pb){
          const f32x16& a = acc[i*2+pb];
          f16x4 o;
          #pragma unroll
          for (int r=0;r<4;++r) o[r] = (_Float16)gelu_fast(a[q2*4+r] + bp2[r]);
          *(f16x4*)(dst + pb*512) = o;
        }
      }
    }
    __syncthreads();
  }

  {
    f32x16 acc[4];
    mlp_pass4<16>(WB + 290816, buf, lane, w, acc);
    __syncthreads();
    #pragma unroll
    for (int i=0;i<2;++i){
      const int F = w*64 + i*32;
      #pragma unroll
      for (int reg=0;reg<16;++reg){
        int f = F + (reg&3) + 8*(reg>>2) + 4*hi;
        if (f < 200){
          float bias = biasAll[1280 + f];
          buf[f*72 + p31]      = (_Float16)(acc[i*2+0][reg] + bias);
          buf[f*72 + 32 + p31] = (_Float16)(acc[i*2+1][reg] + bias);
        }
      }
    }
  }
  __syncthreads();

  {
    const int p = t & 63; const int hd = t >> 6;
    auto KL = [&](int col)->float { return (float)buf[col*72 + p]; };
    const float L2E = 1.4426950408889634f;
    float g0=KL(196),g1=KL(197),g2=KL(198),g3=KL(199);
    float gm = fmaxf(fmaxf(g0,g1),fmaxf(g2,g3));
    float e0=exp2f((g0-gm)*L2E),e1=exp2f((g1-gm)*L2E),
          e2=exp2f((g2-gm)*L2E),e3=exp2f((g3-gm)*L2E);
    float gate = ((hd==0)?e0:(hd==1)?e1:(hd==2)?e2:e3)/(e0+e1+e2+e3);
    float m = -1e30f;
    #pragma unroll
    for (int k=0;k<49;++k) m = fmaxf(m, KL(hd*49+k));
    float s = 0.f;
    float ev[49];
    #pragma unroll
    for (int k=0;k<49;++k){ float e=exp2f((KL(hd*49+k)-m)*L2E); s+=e; ev[k]=e; }
    float sc = gate/s;
    #pragma unroll
    for (int k=0;k<49;++k) buf[(hd*49+k)*72 + p] = (_Float16)(ev[k]*sc);
  }
  __syncthreads();

  {
    float kv[13];
    #pragma unroll
    for (int j=0;j<13;++j){
      int i = t + j*256;
      if (i < 3136){
        int k = i >> 6, p = i & 63;
        kv[j] = (float)buf[k*72+p] + (float)buf[(49+k)*72+p]
              + (float)buf[(98+k)*72+p] + (float)buf[(147+k)*72+p];
      }
    }
    __syncthreads();
    #pragma unroll
    for (int j=0;j<13;++j){
      int i = t + j*256;
      if (i < 3136){
        int k = i >> 6, p = i & 63;
        buf[k*72+p] = (_Float16)kv[j];
      }
    }
  }
  __syncthreads();

  if (t < 192){
    const int c = t >> 6; const int p = t & 63;
    const int px = blockIdx.x*64 + p;
    const int y = px / HWD; const int x = px - y*HWD;
    float lx = (x+0.5f)*0.25f - 0.5f;
    float ly = (y+0.5f)*0.25f - 0.5f;
    int cxi = (int)fminf(fmaxf(rintf(lx),0.f),95.f);
    int cyi = (int)fminf(fmaxf(rintf(ly),0.f),95.f);
    const float* lrc = lr + c*LRPIX;
    float acc = 0.f;
    bool interior = (cxi>=3 && cxi<=92 && cyi>=3 && cyi<=92);
    if (__all(interior)){
      const float* lrb = lrc + (cyi-3)*LWI + (cxi-3);
      #pragma unroll
      for (int k=0;k<49;++k){
        float km = (float)buf[k*72+p];
        acc = fmaf(km, lrb[(k/7)*LWI + (k - (k/7)*7)], acc);
      }
    } else {
      #pragma unroll
      for (int k=0;k<49;++k){
        float km = (float)buf[k*72+p];
        int oy = k/7 - 3, ox = k - (k/7)*7 - 3;
        int nyy = min(max(cyi+oy,0),95), nxx = min(max(cxi+ox,0),95);
        acc = fmaf(km, lrc[nyy*LWI+nxx], acc);
      }
    }
    sr[c*NPIX + px] = acc;
  }
}

// ---- refiner (r12 config): one block per (16x16 tile, group), 256 thr, f32 ----
__global__ __launch_bounds__(256) void refiner_group_kernel(
  const float* __restrict__ lr, const float* __restrict__ srg,
  const float* __restrict__ w0, const float* __restrict__ b0,
  const float* __restrict__ w1, const float* __restrict__ b1,
  const float* __restrict__ w2, const float* __restrict__ b2,
  float* __restrict__ resW)
{
  __shared__ float x6s[2][22][26];
  __shared__ float r1a[16][20][20];
  __shared__ float r1b[16][18][20];
  const int g = blockIdx.z;
  const int tid = threadIdx.x;
  const int gx0 = blockIdx.x*16, gy0 = blockIdx.y*16;

  for (int i = tid; i < 2*22*22; i += 256){
    int ic = i / 484; int rem = i - ic*484; int yy = rem / 22; int xx = rem - yy*22;
    int ch = g*2 + ic;
    int gy = gy0 - 3 + yy, gx = gx0 - 3 + xx;
    float v = 0.f;
    if (gy>=0 && gy<HWD && gx>=0 && gx<HWD){
      int c = (ch<3)?ch:(ch-3);
      float lu = lr_up_at(lr, c, gy, gx);
      v = (ch < 3) ? lu : (srg[c*NPIX + gy*HWD + gx] - lu);
    }
    x6s[ic][yy][xx] = v;
  }
  __syncthreads();

  for (int task = tid; task < 320; task += 256){
    int o = task / 20; int yy = task - o*20;
    int og = g*16 + o;
    float bias = b0[og];
    float acc[20];
    #pragma unroll
    for (int j=0;j<20;++j) acc[j] = bias;
    #pragma unroll
    for (int ic=0; ic<2; ++ic){
      #pragma unroll
      for (int dyy=0; dyy<3; ++dyy){
        float row[22];
        #pragma unroll
        for (int j=0;j<22;++j) row[j] = x6s[ic][yy+dyy][j];
        #pragma unroll
        for (int dxx=0; dxx<3; ++dxx){
          float wv = w0[((og*2+ic)*3+dyy)*3+dxx];
          #pragma unroll
          for (int j=0;j<20;++j) acc[j] = fmaf(wv, row[j+dxx], acc[j]);
        }
      }
    }
    int gyy = gy0 - 2 + yy;
    bool rok = (gyy>=0 && gyy<HWD);
    #pragma unroll
    for (int j=0;j<20;++j){
      int gxx = gx0 - 2 + j;
      r1a[o][yy][j] = (rok && gxx>=0 && gxx<HWD) ? gelu_fast(acc[j]) : 0.f;
    }
  }
  __syncthreads();

  for (int task = tid; task < 288; task += 256){
    int o = task / 18; int yy = task - o*18;
    int og = g*16 + o;
    float bias = b1[og];
    float acc[18];
    #pragma unroll
    for (int j=0;j<18;++j) acc[j] = bias;
    for (int ic=0; ic<16; ++ic){
      #pragma unroll
      for (int dyy=0; dyy<3; ++dyy){
        float row[20];
        #pragma unroll
        for (int q=0;q<5;++q)
          *(float4*)&row[q*4] = *(const float4*)&r1a[ic][yy+dyy][q*4];
        #pragma unroll
        for (int dxx=0; dxx<3; ++dxx){
          float wv = w1[((og*16+ic)*3+dyy)*3+dxx];
          #pragma unroll
          for (int j=0;j<18;++j) acc[j] = fmaf(wv, row[j+dxx], acc[j]);
        }
      }
    }
    int gyy = gy0 - 1 + yy;
    bool rok = (gyy>=0 && gyy<HWD);
    #pragma unroll
    for (int j=0;j<18;++j){
      int gxx = gx0 - 1 + j;
      r1b[o][yy][j] = (rok && gxx>=0 && gxx<HWD) ? gelu_fast(acc[j]) : 0.f;
    }
  }
  __syncthreads();

  {
    int ty = tid >> 4, tx = tid & 15;
    float a = b2[g];
    for (int ic=0; ic<16; ++ic){
      #pragma unroll
      for (int dyy=0; dyy<3; ++dyy){
        #pragma unroll
        for (int dxx=0; dxx<3; ++dxx){
          a = fmaf(w2[((g*16+ic)*3+dyy)*3+dxx], r1b[ic][ty+dyy][tx+dxx], a);
        }
      }
    }
    resW[g*NPIX + (gy0+ty)*HWD + gx0+tx] = a;
  }
}

// gray-residual fusion: out = clip(lr_up + gray(sr+res) - gray(lr_up))
__global__ __launch_bounds__(256) void fuse_kernel(
  const float* __restrict__ lr, const float* __restrict__ srg,
  const float* __restrict__ resW, float* __restrict__ out)
{
  int p = blockIdx.x*256 + threadIdx.x;
  int y = p / HWD, x = p - y*HWD;
  float lu[3];
  float d = 0.f;
  const float cf0=0.2989f, cf1=0.587f, cf2=0.114f;
  lu[0] = lr_up_at(lr, 0, y, x);
  lu[1] = lr_up_at(lr, 1, y, x);
  lu[2] = lr_up_at(lr, 2, y, x);
  d += cf0*(srg[0*NPIX+p] + resW[0*NPIX+p] - lu[0]);
  d += cf1*(srg[1*NPIX+p] + resW[1*NPIX+p] - lu[1]);
  d += cf2*(srg[2*NPIX+p] + resW[2*NPIX+p] - lu[2]);
  #pragma unroll
  for (int c=0;c<3;++c){
    float o_ = lu[c] + d;
    out[c*NPIX + p] = fminf(fmaxf(o_, 0.f), 1.f);
  }
}

extern "C" void kernel_launch(void* const* d_in, const int* in_sizes, int n_in,
                              void* d_out, int out_size, void* d_ws, size_t ws_size,
                              hipStream_t stream){
  const float* lr  = (const float*)d_in[0];
  const float* ew0 = (const float*)d_in[1];  const float* eb0 = (const float*)d_in[2];
  const float* ew1 = (const float*)d_in[3];  const float* eb1 = (const float*)d_in[4];
  const float* ew2 = (const float*)d_in[5];  const float* eb2 = (const float*)d_in[6];
  const float* ew3 = (const float*)d_in[7];  const float* eb3 = (const float*)d_in[8];
  const float* cw0 = (const float*)d_in[9];  const float* cb0 = (const float*)d_in[10];
  const float* cw1 = (const float*)d_in[11]; const float* cb1 = (const float*)d_in[12];
  const float* mw0 = (const float*)d_in[13]; const float* mb0 = (const float*)d_in[14];
  const float* mw1 = (const float*)d_in[15]; const float* mb1 = (const float*)d_in[16];
  const float* mw2 = (const float*)d_in[17]; const float* mb2 = (const float*)d_in[18];
  const float* mw3 = (const float*)d_in[19]; const float* mb3 = (const float*)d_in[20];
  const float* mw4 = (const float*)d_in[21]; const float* mb4 = (const float*)d_in[22];
  const float* hkw = (const float*)d_in[23]; const float* hkb = (const float*)d_in[24];
  const float* hgw = (const float*)d_in[25]; const float* hgb = (const float*)d_in[26];
  const float* rw0 = (const float*)d_in[27]; const float* rb0 = (const float*)d_in[28];
  const float* rw1 = (const float*)d_in[29]; const float* rb1 = (const float*)d_in[30];
  const float* rw2 = (const float*)d_in[31]; const float* rb2 = (const float*)d_in[32];

  float* ws = (float*)d_ws;
  _Float16* X0 = (_Float16*)ws;                  // [9216][64] f16
  _Float16* X1 = (_Float16*)(ws + 294912);       // [9216][64] f16
  float* srp   = ws + 589824;                    // [3][384][384] f32
  _Float16* WB = (_Float16*)(ws + 1032192);      // 356352 f16
  _Float16* WC = (_Float16*)(ws + 1210368);      // 110592 f16
  float* biasAll = ws + 1265664;                 // 1536 f32
  float* resW  = ws + 1267200;                   // [3][NPIX] f32
  _Float16* WX = (_Float16*)(ws + 1709568);      // 8192 f16 (1x1 conv weights)

  pack_all<<<1862,256,0,stream>>>(mw0,mw1,mw2,mw3,mw4,hkw,hgw,
      mb0,mb1,mb2,mb3,mb4,hkb,hgb,
      ew1,ew2,ew3, cw0,cw1, WB, biasAll, WC, WX);

  conv3x3_f16out<<<2304,256,0,stream>>>(lr, ew0, eb0, X0);
  conv_mfma_kernel<<<dim3(12,12),256,0,stream>>>(X0, WC, eb1, X1, 0);
  conv_mfma_kernel<<<dim3(12,12),256,0,stream>>>(X1, WC, eb2, X0, 1);
  conv_mfma_kernel<<<dim3(12,12),256,0,stream>>>(X0, WC, eb3, X1, 2);
  conv1x1_pair_mfma<<<144,256,0,stream>>>(X1, WX, cb0, cb1, X0);

  mlp_mfma7_kernel<<<2304,256,0,stream>>>(X0, lr, WB, biasAll, srp);

  refiner_group_kernel<<<dim3(24,24,3),256,0,stream>>>(lr, srp,
      rw0,rb0, rw1,rb1, rw2,rb2, resW);
  fuse_kernel<<<576,256,0,stream>>>(lr, srp, resW, (float*)d_out);
}

// Round 16
// 316.242 us; speedup vs baseline: 1.1515x; 1.0123x over previous
//
#include <hip/hip_runtime.h>
#include <math.h>

#define LWI 96
#define LHI 96
#define HWD 384
#define NPIX 147456
#define LRPIX 9216
#define HID 256

typedef __attribute__((ext_vector_type(8))) _Float16 f16x8;
typedef __attribute__((ext_vector_type(4))) _Float16 f16x4;
typedef __attribute__((ext_vector_type(2))) __fp16 fp16v2;
typedef __attribute__((ext_vector_type(16))) float f32x16;

__device__ __forceinline__ float gelu_fast(float x){
  float x2 = x*x;
  float u = x*(-2.3021181f - 0.1029443f*x2);
  float e = exp2f(u);
  return x * __builtin_amdgcn_rcpf(1.0f + e);
}

// jax.image.resize 'bilinear' (half-pixel, clamp) at scale 4
__device__ __forceinline__ float lr_up_at(const float* __restrict__ lr, int c, int y, int x){
  float sy = (y+0.5f)*0.25f - 0.5f;
  float sx = (x+0.5f)*0.25f - 0.5f;
  float fy = floorf(sy), fx = floorf(sx);
  float ty = sy - fy, tx = sx - fx;
  int y0 = (int)fy, x0 = (int)fx;
  int y0c = min(max(y0,0),LHI-1), y1c = min(max(y0+1,0),LHI-1);
  int x0c = min(max(x0,0),LWI-1), x1c = min(max(x0+1,0),LWI-1);
  const float* p = lr + c*LRPIX;
  float v00 = p[y0c*LWI+x0c], v01 = p[y0c*LWI+x1c];
  float v10 = p[y1c*LWI+x0c], v11 = p[y1c*LWI+x1c];
  return (1.f-ty)*((1.f-tx)*v00 + tx*v01) + ty*((1.f-tx)*v10 + tx*v11);
}

// merged: blocks [0,2304) = first conv (Cin=3, f32 planar -> f16 channel-last);
//         blocks [2304,4166) = pack all weights
__global__ __launch_bounds__(256) void conv0_and_pack(
    const float* __restrict__ in, const float* __restrict__ w,
    const float* __restrict__ b, _Float16* __restrict__ out16,
    const float* __restrict__ mw0, const float* __restrict__ mw1,
    const float* __restrict__ mw2, const float* __restrict__ mw3,
    const float* __restrict__ mw4, const float* __restrict__ hkw,
    const float* __restrict__ hgw,
    const float* __restrict__ mb0, const float* __restrict__ mb1,
    const float* __restrict__ mb2, const float* __restrict__ mb3,
    const float* __restrict__ mb4, const float* __restrict__ hkb,
    const float* __restrict__ hgb,
    const float* __restrict__ cw1, const float* __restrict__ cw2,
    const float* __restrict__ cw3, const float* __restrict__ xw0,
    const float* __restrict__ xw1,
    _Float16* __restrict__ WB, float* __restrict__ biasAll,
    _Float16* __restrict__ WC, _Float16* __restrict__ WX)
{
  if (blockIdx.x < 2304){
    int tid = blockIdx.x*256 + threadIdx.x;
    int o = tid / LRPIX; int rem = tid - o*LRPIX;
    int y = rem / LWI;   int x = rem - y*LWI;
    int ou = __builtin_amdgcn_readfirstlane(o);
    float acc = b[ou];
    const float* wo = w + ou*27;
    for (int i=0;i<3;++i){
      const float* inp = in + i*LRPIX;
      #pragma unroll
      for (int dy=0;dy<3;++dy){
        int yy = y + dy - 1;
        bool yok = (yy>=0 && yy<LHI);
        #pragma unroll
        for (int dx=0;dx<3;++dx){
          int xx = x + dx - 1;
          float v = (yok && xx>=0 && xx<LWI) ? inp[yy*LWI+xx] : 0.0f;
          acc = fmaf(wo[i*9 + dy*3 + dx], v, acc);
        }
      }
    }
    out16[rem*64 + o] = (_Float16)gelu_fast(acc);
    return;
  }
  int i = (blockIdx.x - 2304)*256 + threadIdx.x;
  if (i < 356352){
    int layer, local;
    if (i < 28672){ layer = 0; local = i; }
    else { layer = 1 + ((i-28672)>>16); local = (i-28672)&65535; }
    int ks = local >> 12; int r = local & 4095;
    int cb = r >> 9; int s2 = r & 511; int slot = s2 >> 3; int e = s2 & 7;
    int col = cb*32 + (slot & 31); int g = slot >> 5;
    int k = ks*16 + g*8 + e;
    float v = 0.f;
    if (layer == 0){ if (k < 106) v = mw0[k*256+col]; }
    else if (layer == 1) v = mw1[k*256+col];
    else if (layer == 2) v = mw2[k*256+col];
    else if (layer == 3) v = mw3[k*256+col];
    else if (layer == 4) v = mw4[k*256+col];
    else { if (col < 196) v = hkw[k*196+col]; else if (col < 200) v = hgw[k*4+col-196]; }
    WB[i] = (_Float16)v;
  } else if (i < 357888){
    int j = i - 356352; int layer = j>>8; int col = j&255;
    float v = 0.f;
    if (layer==0) v=mb0[col]; else if (layer==1) v=mb1[col]; else if(layer==2) v=mb2[col];
    else if(layer==3) v=mb3[col]; else if(layer==4) v=mb4[col];
    else { if (col<196) v=hkb[col]; else if(col<200) v=hgb[col-196]; }
    biasAll[j] = v;
  } else if (i < 468480){
    int j = i - 357888;
    int cv = j / 36864; int s2 = j - cv*36864;
    int tkf = s2 >> 9; int s = s2 & 511;
    int tap = tkf >> 3; int ksfb = tkf & 7;
    int ks = ksfb >> 1; int fb = ksfb & 1;
    int slot = s >> 3; int e = s & 7;
    int oc = fb*32 + (slot & 31);
    int ic = ks*16 + (slot>>5)*8 + e;
    int dy = tap/3, dx = tap - (tap/3)*3;
    const float* src = (cv==0)?cw1:(cv==1)?cw2:cw3;
    WC[j] = (_Float16)src[((oc*64+ic)*3+dy)*3+dx];
  } else if (i < 476672){
    int j = i - 468480;
    int cv = j >> 12; int s2 = j & 4095;
    int ks = s2 >> 10; int fb = (s2 >> 9) & 1; int s = s2 & 511;
    int slot = s >> 3; int e = s & 7;
    int oc = fb*32 + (slot & 31);
    int ic = ks*16 + (slot>>5)*8 + e;
    WX[j] = (_Float16)((cv==0) ? xw0[oc*66+ic] : xw1[oc*64+ic]);
  }
}

// ---- MFMA conv3x3 Cin=Cout=64, f16 channel-last in/out, 8x8 px tile/block ----
__global__ __launch_bounds__(256) void conv_mfma_kernel(
    const _Float16* __restrict__ Xin, const _Float16* __restrict__ WC,
    const float* __restrict__ bias, _Float16* __restrict__ Xout, int cv)
{
  __shared__ _Float16 xs[100*64];        // 12.8KB, 16B-chunk XOR swizzle
  __shared__ float red[2][2][64][20];    // 20.5KB padded K-reduce buffer
  const int t = threadIdx.x;
  const int lane = t & 63;
  const int w = __builtin_amdgcn_readfirstlane(t >> 6);  // 0..3
  const int fb = w & 1, kh = w >> 1;
  const int g = lane >> 5;
  const int gx0 = blockIdx.x*8, gy0 = blockIdx.y*8;

  for (int i = t; i < 800; i += 256){
    int sp = i >> 3, c = i & 7;
    int ly = (sp*205)>>11; int lx = sp - ly*10;
    int gy = gy0 - 1 + ly, gx = gx0 - 1 + lx;
    f16x8 v = f16x8{};
    if (gy>=0 && gy<LHI && gx>=0 && gx<LWI)
      v = *(const f16x8*)(Xin + (gy*LWI+gx)*64 + c*8);
    *(f16x8*)(xs + sp*64 + ((c ^ (sp&7))*8)) = v;
  }
  __syncthreads();

  const _Float16* WCc = WC + cv*36864;
  const int p0 = lane & 31;
  const int py0 = p0 >> 3, px0 = p0 & 7;
  f32x16 acc0{}, acc1{};
  #pragma unroll
  for (int tap = 0; tap < 9; ++tap){
    const int dy = tap/3, dx = tap - (tap/3)*3;
    #pragma unroll
    for (int ksl = 0; ksl < 2; ++ksl){
      int ks = kh*2 + ksl;
      f16x8 A = *(const f16x8*)(WCc + ((tap*4+ks)*2+fb)*512 + lane*8);
      int sp0 = (py0+dy)*10 + (px0+dx);
      int sp1 = (py0+4+dy)*10 + (px0+dx);
      int c0 = ks*2 + g;
      f16x8 B0 = *(const f16x8*)(xs + sp0*64 + ((c0 ^ (sp0&7))*8));
      f16x8 B1 = *(const f16x8*)(xs + sp1*64 + ((c0 ^ (sp1&7))*8));
      acc0 = __builtin_amdgcn_mfma_f32_32x32x16_f16(A,B0,acc0,0,0,0);
      acc1 = __builtin_amdgcn_mfma_f32_32x32x16_f16(A,B1,acc1,0,0,0);
    }
  }
  if (kh == 1){
    #pragma unroll
    for (int r4=0;r4<4;++r4){
      float4 v0 = make_float4(acc0[r4*4],acc0[r4*4+1],acc0[r4*4+2],acc0[r4*4+3]);
      float4 v1 = make_float4(acc1[r4*4],acc1[r4*4+1],acc1[r4*4+2],acc1[r4*4+3]);
      *(float4*)&red[fb][0][lane][r4*4] = v0;
      *(float4*)&red[fb][1][lane][r4*4] = v1;
    }
  }
  __syncthreads();
  if (kh == 0){
    #pragma unroll
    for (int ph=0; ph<2; ++ph){
      const f32x16& acc = ph ? acc1 : acc0;
      int py = ph*4 + py0;
      int gpx = (gy0+py)*LWI + (gx0+px0);
      #pragma unroll
      for (int r4=0;r4<4;++r4){
        float4 rr = *(const float4*)&red[fb][ph][lane][r4*4];
        float4 bb = *(const float4*)&bias[fb*32 + 8*r4 + 4*g];
        f16x4 o;
        o[0] = (_Float16)gelu_fast(acc[r4*4+0] + rr.x + bb.x);
        o[1] = (_Float16)gelu_fast(acc[r4*4+1] + rr.y + bb.y);
        o[2] = (_Float16)gelu_fast(acc[r4*4+2] + rr.z + bb.z);
        o[3] = (_Float16)gelu_fast(acc[r4*4+3] + rr.w + bb.w);
        *(f16x4*)(Xout + gpx*64 + fb*32 + 8*r4 + 4*g) = o;
      }
    }
  }
}

// ---- fused MFMA conv1x1 pair ----
__global__ __launch_bounds__(256) void conv1x1_pair_mfma(
    const _Float16* __restrict__ Xin, const _Float16* __restrict__ WX,
    const float* __restrict__ b0, const float* __restrict__ b1,
    _Float16* __restrict__ Xout)
{
  __shared__ _Float16 bufB[4096];
  __shared__ _Float16 bufC[4096];
  const int t = threadIdx.x;
  const int lane = t & 63;
  const int w = __builtin_amdgcn_readfirstlane(t >> 6);
  const int fb = w & 1, ph = w >> 1;
  const int px0 = blockIdx.x * 64;
  const int p31 = lane & 31, hi = lane >> 5;

  #pragma unroll
  for (int h = 0; h < 2; ++h){
    int i = t + h*256;
    int p = i & 63, c = i >> 6;
    f16x8 v = *(const f16x8*)(Xin + (px0+p)*64 + c*8);
    *(f16x8*)(bufB + ((c>>1)*2 + (p>>5))*512 + ((p&31)+32*(c&1))*8) = v;
  }
  __syncthreads();

  {
    f32x16 acc{};
    #pragma unroll
    for (int ks=0; ks<4; ++ks){
      f16x8 A = *(const f16x8*)(WX + (ks*2+fb)*512 + lane*8);
      f16x8 B = *(const f16x8*)(bufB + (ks*2+ph)*512 + lane*8);
      acc = __builtin_amdgcn_mfma_f32_32x32x16_f16(A,B,acc,0,0,0);
    }
    #pragma unroll
    for (int q=0;q<4;++q){
      float4 bb = *(const float4*)&b0[fb*32 + q*8 + 4*hi];
      const float* bp = (const float*)&bb;
      f16x4 o;
      #pragma unroll
      for (int r=0;r<4;++r) o[r] = (_Float16)gelu_fast(acc[q*4+r] + bp[r]);
      _Float16* dst = bufC + ((fb*2+(q>>1))*2 + ph)*512 + (p31 + 32*(q&1))*8 + 4*hi;
      *(f16x4*)dst = o;
    }
  }
  __syncthreads();

  {
    f32x16 acc{};
    #pragma unroll
    for (int ks=0; ks<4; ++ks){
      f16x8 A = *(const f16x8*)(WX + 4096 + (ks*2+fb)*512 + lane*8);
      f16x8 B = *(const f16x8*)(bufC + (ks*2+ph)*512 + lane*8);
      acc = __builtin_amdgcn_mfma_f32_32x32x16_f16(A,B,acc,0,0,0);
    }
    int px = px0 + ph*32 + p31;
    #pragma unroll
    for (int q=0;q<4;++q){
      float4 bb = *(const float4*)&b1[fb*32 + q*8 + 4*hi];
      const float* bp = (const float*)&bb;
      f16x4 o;
      #pragma unroll
      for (int r=0;r<4;++r) o[r] = (_Float16)(acc[q*4+r] + bp[r]);
      *(f16x4*)(Xout + px*64 + fb*32 + q*8 + 4*hi) = o;
    }
  }
}

// wave w computes feats [64w,64w+64) x 64 px; 4 MFMA per ks
template<int NKS>
__device__ __forceinline__ void mlp_pass4(const _Float16* __restrict__ Wl,
    const _Float16* __restrict__ buf, int lane, int w, f32x16 (&acc)[4]){
  acc[0]=f32x16{}; acc[1]=f32x16{}; acc[2]=f32x16{}; acc[3]=f32x16{};
  #pragma unroll
  for (int ks=0; ks<NKS; ++ks){
    const _Float16* wp = Wl + (ks*8 + 2*w)*512 + lane*8;
    f16x8 a0 = *(const f16x8*)(wp);
    f16x8 a1 = *(const f16x8*)(wp + 512);
    const _Float16* bp = buf + ks*1024 + lane*8;
    f16x8 b0 = *(const f16x8*)(bp);
    f16x8 b1 = *(const f16x8*)(bp + 512);
    acc[0] = __builtin_amdgcn_mfma_f32_32x32x16_f16(a0,b0,acc[0],0,0,0);
    acc[1] = __builtin_amdgcn_mfma_f32_32x32x16_f16(a0,b1,acc[1],0,0,0);
    acc[2] = __builtin_amdgcn_mfma_f32_32x32x16_f16(a1,b0,acc[2],0,0,0);
    acc[3] = __builtin_amdgcn_mfma_f32_32x32x16_f16(a1,b1,acc[3],0,0,0);
  }
}

// ---- MFMA MLP v7b: 64 px/block, 4 waves x 64 feats, 32KB in-place,
//      packed f32->f16 cvt (v_cvt_pkrtz) in epilogue ----
__global__ __launch_bounds__(256,4) void mlp_mfma7_kernel(
  const _Float16* __restrict__ feat16, const float* __restrict__ lr,
  const _Float16* __restrict__ WB, const float* __restrict__ biasAll,
  float* __restrict__ sr)
{
  __shared__ _Float16 buf[16384];   // 32KB
  const int t = threadIdx.x;
  const int lane = t & 63;
  const int w = __builtin_amdgcn_readfirstlane(t >> 6);   // 0..3
  const int p31 = lane & 31; const int hi = lane >> 5;

  {
    const int p = lane; const int q = w;
    const int px = blockIdx.x*64 + p;
    const int y = px / HWD; const int x = px - y*HWD;
    float lx = (x+0.5f)*0.25f - 0.5f;
    float ly = (y+0.5f)*0.25f - 0.5f;
    float cxf = fminf(fmaxf(rintf(lx),0.f),95.f);
    float cyf = fminf(fmaxf(rintf(ly),0.f),95.f);
    int base = (int)cyf*LWI + (int)cxf;
    auto zwrite = [&](int k, float v){
      buf[((k>>4)*2 + (p>>5))*512 + ((p&31) + 32*((k>>3)&1))*8 + (k&7)] = (_Float16)v;
    };
    auto zwriteh = [&](int k, _Float16 v){
      buf[((k>>4)*2 + (p>>5))*512 + ((p&31) + 32*((k>>3)&1))*8 + (k&7)] = v;
    };
    if (q < 2){
      const _Float16* fsrc = feat16 + base*64 + q*32;
      #pragma unroll
      for (int j=0;j<32;++j) zwriteh(q*32+j, fsrc[j]);
    } else if (q == 2){
      float xn = (x+0.5f)/384.0f*2.0f - 1.0f;
      float s = sinf(xn*3.14159265358979323846f);
      float c = cosf(xn*3.14159265358979323846f);
      #pragma unroll
      for (int b=0;b<10;++b){
        zwrite(64+4*b+0, s); zwrite(64+4*b+1, c);
        float s2 = 2.f*s*c; float c2 = 1.f - 2.f*s*s;
        s=s2; c=c2;
      }
      zwrite(104, lx-cxf); zwrite(105, ly-cyf);
    } else {
      float yn = (y+0.5f)/384.0f*2.0f - 1.0f;
      float s = sinf(yn*3.14159265358979323846f);
      float c = cosf(yn*3.14159265358979323846f);
      #pragma unroll
      for (int b=0;b<10;++b){
        zwrite(64+4*b+2, s); zwrite(64+4*b+3, c);
        float s2 = 2.f*s*c; float c2 = 1.f - 2.f*s*s;
        s=s2; c=c2;
      }
      #pragma unroll
      for (int k=106;k<112;++k) zwrite(k, 0.f);
    }
  }
  __syncthreads();

  #pragma unroll 1
  for (int L=0; L<5; ++L){
    static const int WOFFS[5] = {0,28672,94208,159744,225280};
    f32x16 acc[4];
    if (L==0) mlp_pass4<7>(WB, buf, lane, w, acc);
    else      mlp_pass4<16>(WB + WOFFS[L], buf, lane, w, acc);
    __syncthreads();
    const float* Bl = biasAll + L*256;
    #pragma unroll
    for (int i=0;i<2;++i){
      const int F = w*64 + i*32;
      #pragma unroll
      for (int q2=0;q2<4;++q2){
        float4 bs = *(const float4*)&Bl[F + q2*8 + 4*hi];
        const float* bp2 = (const float*)&bs;
        int ks2 = (F>>4) + (q2>>1); int g2 = q2&1;
        _Float16* dst = buf + (ks2*2)*512 + (p31 + 32*g2)*8 + 4*hi;
        #pragma unroll
        for (int pb=0;pb<2;++pb){
          const f32x16& a = acc[i*2+pb];
          float g0 = gelu_fast(a[q2*4+0] + bp2[0]);
          float g1 = gelu_fast(a[q2*4+1] + bp2[1]);
          float g2f = gelu_fast(a[q2*4+2] + bp2[2]);
          float g3 = gelu_fast(a[q2*4+3] + bp2[3]);
          fp16v2 lo = __builtin_amdgcn_cvt_pkrtz(g0, g1);
          fp16v2 hi2 = __builtin_amdgcn_cvt_pkrtz(g2f, g3);
          *(fp16v2*)(dst + pb*512)     = lo;
          *(fp16v2*)(dst + pb*512 + 2) = hi2;
        }
      }
    }
    __syncthreads();
  }

  {
    f32x16 acc[4];
    mlp_pass4<16>(WB + 290816, buf, lane, w, acc);
    __syncthreads();
    #pragma unroll
    for (int i=0;i<2;++i){
      const int F = w*64 + i*32;
      #pragma unroll
      for (int reg=0;reg<16;++reg){
        int f = F + (reg&3) + 8*(reg>>2) + 4*hi;
        if (f < 200){
          float bias = biasAll[1280 + f];
          buf[f*72 + p31]      = (_Float16)(acc[i*2+0][reg] + bias);
          buf[f*72 + 32 + p31] = (_Float16)(acc[i*2+1][reg] + bias);
        }
      }
    }
  }
  __syncthreads();

  {
    const int p = t & 63; const int hd = t >> 6;
    auto KL = [&](int col)->float { return (float)buf[col*72 + p]; };
    const float L2E = 1.4426950408889634f;
    float g0=KL(196),g1=KL(197),g2=KL(198),g3=KL(199);
    float gm = fmaxf(fmaxf(g0,g1),fmaxf(g2,g3));
    float e0=exp2f((g0-gm)*L2E),e1=exp2f((g1-gm)*L2E),
          e2=exp2f((g2-gm)*L2E),e3=exp2f((g3-gm)*L2E);
    float gate = ((hd==0)?e0:(hd==1)?e1:(hd==2)?e2:e3)/(e0+e1+e2+e3);
    float m = -1e30f;
    #pragma unroll
    for (int k=0;k<49;++k) m = fmaxf(m, KL(hd*49+k));
    float s = 0.f;
    float ev[49];
    #pragma unroll
    for (int k=0;k<49;++k){ float e=exp2f((KL(hd*49+k)-m)*L2E); s+=e; ev[k]=e; }
    float sc = gate/s;
    #pragma unroll
    for (int k=0;k<49;++k) buf[(hd*49+k)*72 + p] = (_Float16)(ev[k]*sc);
  }
  __syncthreads();

  {
    float kv[13];
    #pragma unroll
    for (int j=0;j<13;++j){
      int i = t + j*256;
      if (i < 3136){
        int k = i >> 6, p = i & 63;
        kv[j] = (float)buf[k*72+p] + (float)buf[(49+k)*72+p]
              + (float)buf[(98+k)*72+p] + (float)buf[(147+k)*72+p];
      }
    }
    __syncthreads();
    #pragma unroll
    for (int j=0;j<13;++j){
      int i = t + j*256;
      if (i < 3136){
        int k = i >> 6, p = i & 63;
        buf[k*72+p] = (_Float16)kv[j];
      }
    }
  }
  __syncthreads();

  if (t < 192){
    const int c = t >> 6; const int p = t & 63;
    const int px = blockIdx.x*64 + p;
    const int y = px / HWD; const int x = px - y*HWD;
    float lx = (x+0.5f)*0.25f - 0.5f;
    float ly = (y+0.5f)*0.25f - 0.5f;
    int cxi = (int)fminf(fmaxf(rintf(lx),0.f),95.f);
    int cyi = (int)fminf(fmaxf(rintf(ly),0.f),95.f);
    const float* lrc = lr + c*LRPIX;
    float acc = 0.f;
    bool interior = (cxi>=3 && cxi<=92 && cyi>=3 && cyi<=92);
    if (__all(interior)){
      const float* lrb = lrc + (cyi-3)*LWI + (cxi-3);
      #pragma unroll
      for (int k=0;k<49;++k){
        float km = (float)buf[k*72+p];
        acc = fmaf(km, lrb[(k/7)*LWI + (k - (k/7)*7)], acc);
      }
    } else {
      #pragma unroll
      for (int k=0;k<49;++k){
        float km = (float)buf[k*72+p];
        int oy = k/7 - 3, ox = k - (k/7)*7 - 3;
        int nyy = min(max(cyi+oy,0),95), nxx = min(max(cxi+ox,0),95);
        acc = fmaf(km, lrc[nyy*LWI+nxx], acc);
      }
    }
    sr[c*NPIX + px] = acc;
  }
}

// ---- refiner (r12 config): one block per (16x16 tile, group), 256 thr, f32 ----
__global__ __launch_bounds__(256) void refiner_group_kernel(
  const float* __restrict__ lr, const float* __restrict__ srg,
  const float* __restrict__ w0, const float* __restrict__ b0,
  const float* __restrict__ w1, const float* __restrict__ b1,
  const float* __restrict__ w2, const float* __restrict__ b2,
  float* __restrict__ resW)
{
  __shared__ float x6s[2][22][26];
  __shared__ float r1a[16][20][20];
  __shared__ float r1b[16][18][20];
  const int g = blockIdx.z;
  const int tid = threadIdx.x;
  const int gx0 = blockIdx.x*16, gy0 = blockIdx.y*16;

  for (int i = tid; i < 2*22*22; i += 256){
    int ic = i / 484; int rem = i - ic*484; int yy = rem / 22; int xx = rem - yy*22;
    int ch = g*2 + ic;
    int gy = gy0 - 3 + yy, gx = gx0 - 3 + xx;
    float v = 0.f;
    if (gy>=0 && gy<HWD && gx>=0 && gx<HWD){
      int c = (ch<3)?ch:(ch-3);
      float lu = lr_up_at(lr, c, gy, gx);
      v = (ch < 3) ? lu : (srg[c*NPIX + gy*HWD + gx] - lu);
    }
    x6s[ic][yy][xx] = v;
  }
  __syncthreads();

  for (int task = tid; task < 320; task += 256){
    int o = task / 20; int yy = task - o*20;
    int og = g*16 + o;
    float bias = b0[og];
    float acc[20];
    #pragma unroll
    for (int j=0;j<20;++j) acc[j] = bias;
    #pragma unroll
    for (int ic=0; ic<2; ++ic){
      #pragma unroll
      for (int dyy=0; dyy<3; ++dyy){
        float row[22];
        #pragma unroll
        for (int j=0;j<22;++j) row[j] = x6s[ic][yy+dyy][j];
        #pragma unroll
        for (int dxx=0; dxx<3; ++dxx){
          float wv = w0[((og*2+ic)*3+dyy)*3+dxx];
          #pragma unroll
          for (int j=0;j<20;++j) acc[j] = fmaf(wv, row[j+dxx], acc[j]);
        }
      }
    }
    int gyy = gy0 - 2 + yy;
    bool rok = (gyy>=0 && gyy<HWD);
    #pragma unroll
    for (int j=0;j<20;++j){
      int gxx = gx0 - 2 + j;
      r1a[o][yy][j] = (rok && gxx>=0 && gxx<HWD) ? gelu_fast(acc[j]) : 0.f;
    }
  }
  __syncthreads();

  for (int task = tid; task < 288; task += 256){
    int o = task / 18; int yy = task - o*18;
    int og = g*16 + o;
    float bias = b1[og];
    float acc[18];
    #pragma unroll
    for (int j=0;j<18;++j) acc[j] = bias;
    for (int ic=0; ic<16; ++ic){
      #pragma unroll
      for (int dyy=0; dyy<3; ++dyy){
        float row[20];
        #pragma unroll
        for (int q=0;q<5;++q)
          *(float4*)&row[q*4] = *(const float4*)&r1a[ic][yy+dyy][q*4];
        #pragma unroll
        for (int dxx=0; dxx<3; ++dxx){
          float wv = w1[((og*16+ic)*3+dyy)*3+dxx];
          #pragma unroll
          for (int j=0;j<18;++j) acc[j] = fmaf(wv, row[j+dxx], acc[j]);
        }
      }
    }
    int gyy = gy0 - 1 + yy;
    bool rok = (gyy>=0 && gyy<HWD);
    #pragma unroll
    for (int j=0;j<18;++j){
      int gxx = gx0 - 1 + j;
      r1b[o][yy][j] = (rok && gxx>=0 && gxx<HWD) ? gelu_fast(acc[j]) : 0.f;
    }
  }
  __syncthreads();

  {
    int ty = tid >> 4, tx = tid & 15;
    float a = b2[g];
    for (int ic=0; ic<16; ++ic){
      #pragma unroll
      for (int dyy=0; dyy<3; ++dyy){
        #pragma unroll
        for (int dxx=0; dxx<3; ++dxx){
          a = fmaf(w2[((g*16+ic)*3+dyy)*3+dxx], r1b[ic][ty+dyy][tx+dxx], a);
        }
      }
    }
    resW[g*NPIX + (gy0+ty)*HWD + gx0+tx] = a;
  }
}

// gray-residual fusion: out = clip(lr_up + gray(sr+res) - gray(lr_up))
__global__ __launch_bounds__(256) void fuse_kernel(
  const float* __restrict__ lr, const float* __restrict__ srg,
  const float* __restrict__ resW, float* __restrict__ out)
{
  int p = blockIdx.x*256 + threadIdx.x;
  int y = p / HWD, x = p - y*HWD;
  float lu[3];
  float d = 0.f;
  const float cf0=0.2989f, cf1=0.587f, cf2=0.114f;
  lu[0] = lr_up_at(lr, 0, y, x);
  lu[1] = lr_up_at(lr, 1, y, x);
  lu[2] = lr_up_at(lr, 2, y, x);
  d += cf0*(srg[0*NPIX+p] + resW[0*NPIX+p] - lu[0]);
  d += cf1*(srg[1*NPIX+p] + resW[1*NPIX+p] - lu[1]);
  d += cf2*(srg[2*NPIX+p] + resW[2*NPIX+p] - lu[2]);
  #pragma unroll
  for (int c=0;c<3;++c){
    float o_ = lu[c] + d;
    out[c*NPIX + p] = fminf(fmaxf(o_, 0.f), 1.f);
  }
}

extern "C" void kernel_launch(void* const* d_in, const int* in_sizes, int n_in,
                              void* d_out, int out_size, void* d_ws, size_t ws_size,
                              hipStream_t stream){
  const float* lr  = (const float*)d_in[0];
  const float* ew0 = (const float*)d_in[1];  const float* eb0 = (const float*)d_in[2];
  const float* ew1 = (const float*)d_in[3];  const float* eb1 = (const float*)d_in[4];
  const float* ew2 = (const float*)d_in[5];  const float* eb2 = (const float*)d_in[6];
  const float* ew3 = (const float*)d_in[7];  const float* eb3 = (const float*)d_in[8];
  const float* cw0 = (const float*)d_in[9];  const float* cb0 = (const float*)d_in[10];
  const float* cw1 = (const float*)d_in[11]; const float* cb1 = (const float*)d_in[12];
  const float* mw0 = (const float*)d_in[13]; const float* mb0 = (const float*)d_in[14];
  const float* mw1 = (const float*)d_in[15]; const float* mb1 = (const float*)d_in[16];
  const float* mw2 = (const float*)d_in[17]; const float* mb2 = (const float*)d_in[18];
  const float* mw3 = (const float*)d_in[19]; const float* mb3 = (const float*)d_in[20];
  const float* mw4 = (const float*)d_in[21]; const float* mb4 = (const float*)d_in[22];
  const float* hkw = (const float*)d_in[23]; const float* hkb = (const float*)d_in[24];
  const float* hgw = (const float*)d_in[25]; const float* hgb = (const float*)d_in[26];
  const float* rw0 = (const float*)d_in[27]; const float* rb0 = (const float*)d_in[28];
  const float* rw1 = (const float*)d_in[29]; const float* rb1 = (const float*)d_in[30];
  const float* rw2 = (const float*)d_in[31]; const float* rb2 = (const float*)d_in[32];

  float* ws = (float*)d_ws;
  _Float16* X0 = (_Float16*)ws;                  // [9216][64] f16
  _Float16* X1 = (_Float16*)(ws + 294912);       // [9216][64] f16
  float* srp   = ws + 589824;                    // [3][384][384] f32
  _Float16* WB = (_Float16*)(ws + 1032192);      // 356352 f16
  _Float16* WC = (_Float16*)(ws + 1210368);      // 110592 f16
  float* biasAll = ws + 1265664;                 // 1536 f32
  float* resW  = ws + 1267200;                   // [3][NPIX] f32
  _Float16* WX = (_Float16*)(ws + 1709568);      // 8192 f16 (1x1 conv weights)

  conv0_and_pack<<<4166,256,0,stream>>>(lr, ew0, eb0, X0,
      mw0,mw1,mw2,mw3,mw4,hkw,hgw,
      mb0,mb1,mb2,mb3,mb4,hkb,hgb,
      ew1,ew2,ew3, cw0,cw1, WB, biasAll, WC, WX);

  conv_mfma_kernel<<<dim3(12,12),256,0,stream>>>(X0, WC, eb1, X1, 0);
  conv_mfma_kernel<<<dim3(12,12),256,0,stream>>>(X1, WC, eb2, X0, 1);
  conv_mfma_kernel<<<dim3(12,12),256,0,stream>>>(X0, WC, eb3, X1, 2);
  conv1x1_pair_mfma<<<144,256,0,stream>>>(X1, WX, cb0, cb1, X0);

  mlp_mfma7_kernel<<<2304,256,0,stream>>>(X0, lr, WB, biasAll, srp);

  refiner_group_kernel<<<dim3(24,24,3),256,0,stream>>>(lr, srp,
      rw0,rb0, rw1,rb1, rw2,rb2, resW);
  fuse_kernel<<<576,256,0,stream>>>(lr, srp, resW, (float*)d_out);
}